// Round 6
// baseline (1013.967 us; speedup 1.0000x reference)
//
#include <hip/hip_runtime.h>
#include <math.h>

#define Bc 8
#define Lc 4096
#define Hc 8
#define Dc 64
#define NCH 16             // equal-WORK chunks (sqrt-spaced causal boundaries)
#define VCH 16
#define VROWS (Lc / VCH)   // 256 rows per cumsum chunk

// equal-work causal chunk boundaries: b_c ~= L*(1-sqrt(1-c/16)), 64-aligned
__constant__ int c_cb[NCH + 1] =
    {0, 128, 256, 384, 576, 704, 832, 1024, 1216, 1408,
     1600, 1792, 2048, 2304, 2624, 3072, 4096};

// ---------------------------------------------------------------- helpers
template<int CTRL>
__device__ __forceinline__ float dpp_mov(float v) {
    return __int_as_float(__builtin_amdgcn_update_dpp(
        0, __float_as_int(v), CTRL, 0xF, 0xF, true));
}
template<int CTRL>
__device__ __forceinline__ float dpp_radd(float v) {
    return v + dpp_mov<CTRL>(v);
}
__device__ __forceinline__ float row16_sum(float p) {
    p = dpp_radd<0x128>(p); p = dpp_radd<0x124>(p);
    p = dpp_radd<0x122>(p); p = dpp_radd<0x121>(p);
    return p;
}
__device__ __forceinline__ float wmax64(float v) {
    v = fmaxf(v, dpp_mov<0x128>(v));
    v = fmaxf(v, dpp_mov<0x124>(v));
    v = fmaxf(v, dpp_mov<0x122>(v));
    v = fmaxf(v, dpp_mov<0x121>(v));
    v = fmaxf(v, __shfl_xor(v, 16, 64));
    return fmaxf(v, __shfl_xor(v, 32, 64));
}
__device__ __forceinline__ float wsum64(float v) {
    v = row16_sum(v);
    v += __shfl_xor(v, 16, 64);
    return v + __shfl_xor(v, 32, 64);
}
__device__ __forceinline__ unsigned short f2bf(float f) {  // RNE fp32->bf16
    unsigned int u = __float_as_uint(f);
    u += 0x7FFFu + ((u >> 16) & 1u);
    return (unsigned short)(u >> 16);
}
__device__ __forceinline__ float bf2f(unsigned short s) {
    return __uint_as_float(((unsigned int)s) << 16);
}

// ---------------------------------------------------------------- kernel 1
template<int S>
__global__ __launch_bounds__(256) void k_meas_t(
    const float* __restrict__ Q, const float* __restrict__ K,
    const int* __restrict__ idx, float* __restrict__ M)
{
    constexpr int NIT = (S + 3) / 4;
    int b = blockIdx.z, h = blockIdx.y;
    int w = threadIdx.x >> 6, lane = threadIdx.x & 63;
    int q = blockIdx.x * 4 + w;
    int grp = lane >> 4, gl = lane & 15;

    const float4 qv = *(const float4*)(Q + (((size_t)b * Lc + q) * Hc + h) * Dc + gl * 4);
    const int* ip = idx + (size_t)q * S + grp;
    const float* Kb = K + ((size_t)b * Lc * Hc + h) * Dc + gl * 4;

    int rows[NIT];
    #pragma unroll
    for (int it = 0; it < NIT - 1; it++) rows[it] = ip[it * 4];
    {
        int s = 4 * (NIT - 1) + grp;
        rows[NIT - 1] = ip[(s < S) ? 4 * (NIT - 1) : (S - 1 - grp)];
    }

    float mloc = -INFINITY, sloc = 0.f;
    #pragma unroll
    for (int it = 0; it < NIT; it++) {
        const float4 kw = *(const float4*)(Kb + ((size_t)rows[it] << 9));
        float p = kw.x * qv.x + kw.y * qv.y + kw.z * qv.z + kw.w * qv.w;
        p = row16_sum(p);
        int s = it * 4 + grp;
        if (s < S) { mloc = fmaxf(mloc, p); sloc += p; }
    }
    mloc = fmaxf(mloc, __shfl_xor(mloc, 16, 64));
    mloc = fmaxf(mloc, __shfl_xor(mloc, 32, 64));
    sloc += __shfl_xor(sloc, 16, 64);
    sloc += __shfl_xor(sloc, 32, 64);

    if (lane == 0)
        M[((size_t)(b * Hc + h)) * Lc + q] = mloc - sloc * (1.0f / (float)Lc);
}

__global__ __launch_bounds__(256) void k_meas_dyn(
    const float* __restrict__ Q, const float* __restrict__ K,
    const int* __restrict__ idx, float* __restrict__ M, int S)
{
    int b = blockIdx.z, h = blockIdx.y;
    int w = threadIdx.x >> 6, lane = threadIdx.x & 63;
    int q = blockIdx.x * 4 + w;
    int grp = lane >> 4, gl = lane & 15;

    const float4 qv = *(const float4*)(Q + (((size_t)b * Lc + q) * Hc + h) * Dc + gl * 4);
    const int* ip = idx + (size_t)q * S;
    const float* Kb = K + ((size_t)b * Lc * Hc + h) * Dc + gl * 4;

    float mloc = -INFINITY, sloc = 0.f;
    int niter = (S + 3) >> 2;
    for (int it = 0; it < niter; it++) {
        int s = it * 4 + grp;
        int ii = s < S ? s : S - 1;
        int row = ip[ii];
        const float4 kw = *(const float4*)(Kb + ((size_t)row << 9));
        float p = kw.x * qv.x + kw.y * qv.y + kw.z * qv.z + kw.w * qv.w;
        p = row16_sum(p);
        if (s < S) { mloc = fmaxf(mloc, p); sloc += p; }
    }
    mloc = fmaxf(mloc, __shfl_xor(mloc, 16, 64));
    mloc = fmaxf(mloc, __shfl_xor(mloc, 32, 64));
    sloc += __shfl_xor(sloc, 16, 64);
    sloc += __shfl_xor(sloc, 32, 64);
    if (lane == 0)
        M[((size_t)(b * Hc + h)) * Lc + q] = mloc - sloc * (1.0f / (float)Lc);
}

// ---------------------------------------------------------------- kernel 2
// top-U selection, then sort indices ASCENDING (order irrelevant to the
// reference's scatter; gives attn2 sorted query lists for tight cutoffs).
__global__ __launch_bounds__(256) void k_topk(
    const float* __restrict__ M, int* __restrict__ top, int U)
{
    int bh = blockIdx.x;
    int tid = threadIdx.x;
    const float* m = M + (size_t)bh * Lc;

    unsigned long long key[16];
    #pragma unroll
    for (int j = 0; j < 16; j++) {
        int i = tid * 16 + j;
        unsigned int u = __float_as_uint(m[i]);
        u ^= (unsigned int)(((int)u >> 31)) | 0x80000000u;
        key[j] = ((unsigned long long)u << 32) | (unsigned int)i;
    }
    unsigned long long myb = key[0];
    #pragma unroll
    for (int j = 1; j < 16; j++) myb = key[j] > myb ? key[j] : myb;

    __shared__ unsigned long long swave[2][4];
    __shared__ int swin[256];

    for (int u = 0; u < U; u++) {
        unsigned long long wmax = myb;
        #pragma unroll
        for (int o = 32; o >= 1; o >>= 1) {
            unsigned long long t = __shfl_xor(wmax, o, 64);
            wmax = t > wmax ? t : wmax;
        }
        if ((tid & 63) == 0) swave[u & 1][tid >> 6] = wmax;
        __syncthreads();
        unsigned long long w0 = swave[u & 1][0], w1 = swave[u & 1][1];
        unsigned long long w2 = swave[u & 1][2], w3 = swave[u & 1][3];
        unsigned long long a = w0 > w1 ? w0 : w1;
        unsigned long long c = w2 > w3 ? w2 : w3;
        unsigned long long win = a > c ? a : c;
        int widx = (int)(win & 0xFFFFFFFFu);
        if (tid == 0) swin[u] = widx;
        if (tid == (widx >> 4)) {
            #pragma unroll
            for (int j = 0; j < 16; j++) if (j == (widx & 15)) key[j] = 0ull;
            unsigned long long b2 = key[0];
            #pragma unroll
            for (int j = 1; j < 16; j++) b2 = key[j] > b2 ? key[j] : b2;
            myb = b2;
        }
    }
    __syncthreads();
    for (int ph = 0; ph < U; ph++) {
        int i = 2 * tid + (ph & 1);
        if (i + 1 < U) {
            int a = swin[i], b2 = swin[i + 1];
            if (a > b2) { swin[i] = b2; swin[i + 1] = a; }
        }
        __syncthreads();
    }
    if (tid < U) top[(size_t)bh * U + tid] = swin[tid];
}

// ---------------------------------------------------------------- kernel 3a
__global__ __launch_bounds__(256) void k_vsum(
    const float* __restrict__ V, float* __restrict__ bsum)
{
    int b = blockIdx.z, h = blockIdx.y, c = blockIdx.x;
    int d = threadIdx.x & 63, g = threadIdx.x >> 6;
    __shared__ float part[4][64];
    float s = 0.f;
    int r0 = c * VROWS;
    for (int r = r0 + g; r < r0 + VROWS; r += 4)
        s += V[(((size_t)b * Lc + r) * Hc + h) * Dc + d];
    part[g][d] = s;
    __syncthreads();
    if (g == 0)
        bsum[(((size_t)(b * Hc + h)) * VCH + c) * 64 + d] =
            part[0][d] + part[1][d] + part[2][d] + part[3][d];
}

// ---------------------------------------------------------------- kernel 3b
// scan within each 256-row chunk; V rows cached in registers (kills 2nd read)
__global__ __launch_bounds__(256) void k_scan(
    const float* __restrict__ V, const float* __restrict__ bsum,
    float* __restrict__ out)
{
    int b = blockIdx.z, h = blockIdx.y, c = blockIdx.x;
    int d = threadIdx.x & 63, g = threadIdx.x >> 6;
    int bh = b * Hc + h;
    __shared__ float gtot[4][64];
    __shared__ float goff[4][64];

    float base = 0.f;
    for (int cc = 0; cc < c; cc++)
        base += bsum[((size_t)bh * VCH + cc) * 64 + d];

    int gs = c * VROWS + g * 64;
    const float* vb = V + (((size_t)b * Lc + gs) * Hc + h) * Dc + d;

    float vloc[64];
    float gsum = 0.f;
    #pragma unroll
    for (int i = 0; i < 64; i++) {
        vloc[i] = vb[(size_t)i * (Hc * Dc)];
        gsum += vloc[i];
    }
    gtot[g][d] = gsum;
    __syncthreads();
    if (g == 0) {
        float run = base;
        for (int gg = 0; gg < 4; gg++) { goff[gg][d] = run; run += gtot[gg][d]; }
    }
    __syncthreads();
    float run = goff[g][d];
    float* ob = out + (((size_t)b * Lc + gs) * Hc + h) * Dc + d;
    #pragma unroll
    for (int i = 0; i < 64; i++) {
        run += vloc[i];
        ob[(size_t)i * (Hc * Dc)] = run;
    }
}

// ---------------------------------------------------------------- kernel 4
// flash attention over selected (globally sorted) queries.
// 512-thread blocks (8 waves share one staged tile): 8 slots/wave (-33%
// chain), LDS 56.4KB -> 2 blocks/CU = 16 waves/CU. R2-exact fp32 math.
__global__ __launch_bounds__(512, 4) void k_attn2(
    const float* __restrict__ Q, const float* __restrict__ K,
    const float* __restrict__ V, const int* __restrict__ top,
    unsigned short* __restrict__ Opart, float* __restrict__ Mp,
    float* __restrict__ Lp, int U)
{
    int b = blockIdx.z, h = blockIdx.y, c = blockIdx.x;
    int bh = b * Hc + h;
    int tid = threadIdx.x;
    int lane = tid & 63, g = tid >> 6;          // g = wave id 0..7

    __shared__ float4 sK4[64][16];   // 16KB  row=key, col=lb^(key&7)
    __shared__ float4 sV4[64][16];   // 16KB  row=d, col=(key>>2)^(d&7)
    __shared__ float  sQ[48][64];    // 12KB
    __shared__ float  sP[48][64];    // 12KB  (row u touched only by wave u%8)
    __shared__ int    sqi[48];

    if (tid < U) sqi[tid] = top[(size_t)bh * U + tid];
    __syncthreads();
    for (int u = g; u < U; u += 8)
        sQ[u][lane] = Q[(((size_t)b * Lc + sqi[u]) * Hc + h) * Dc + lane] * 0.125f;

    int qbm = sqi[U - 1];            // globally sorted -> max q
    // 8 strided slots per wave; invalid -> dup of slot 0 (smallest span,
    // so dup work is negligible; dup writes same value to same address)
    int uu[8], qq[8];
    #pragma unroll
    for (int i = 0; i < 8; i++) {
        int u = g + 8 * i;
        uu[i] = (u < U) ? u : g;
        qq[i] = sqi[uu[i]];
    }
    int gmax0 = max(max(qq[0], qq[1]), max(qq[2], qq[3]));
    int gmax1 = max(max(qq[4], qq[5]), max(qq[6], qq[7]));

    float m_r[8], l_r[8], o_r[8];
    #pragma unroll
    for (int i = 0; i < 8; i++) { m_r[i] = -INFINITY; l_r[i] = 0.f; o_r[i] = 0.f; }

    int k0c = c_cb[c], k1c = c_cb[c + 1];
    int ntile = 0;
    if (qbm >= k0c) ntile = (min(qbm, k1c - 1) - k0c) / 64 + 1;
    int kswz = lane & 7;

    for (int t = 0; t < ntile; t++) {
        int k0 = k0c + t * 64;
        __syncthreads();   // previous tile consumed; sQ/sqi writes ordered
        {   // stage: wave g covers dims g*8 .. g*8+7 (2 float4 per thread)
            const float* kp = K + (((size_t)b * Lc + k0 + lane) * Hc + h) * Dc + g * 8;
            const float* vp = V + (((size_t)b * Lc + k0 + lane) * Hc + h) * Dc + g * 8;
            #pragma unroll
            for (int i = 0; i < 2; i++) {
                float4 kw = *(const float4*)(kp + i * 4);
                float4 vw = *(const float4*)(vp + i * 4);
                int lb = g * 2 + i;
                sK4[lane][lb ^ kswz] = kw;
                int d0 = lb * 4;
                ((float*)&sV4[d0 + 0][(lane >> 2) ^ ((d0 + 0) & 7)])[lane & 3] = vw.x;
                ((float*)&sV4[d0 + 1][(lane >> 2) ^ ((d0 + 1) & 7)])[lane & 3] = vw.y;
                ((float*)&sV4[d0 + 2][(lane >> 2) ^ ((d0 + 2) & 7)])[lane & 3] = vw.z;
                ((float*)&sV4[d0 + 3][(lane >> 2) ^ ((d0 + 3) & 7)])[lane & 3] = vw.w;
            }
        }
        __syncthreads();

#define GROUP(j0, gmax)                                                      \
        if (k0 <= gmax) {                                                    \
            float s0 = 0.f, s1 = 0.f, s2 = 0.f, s3 = 0.f;                    \
            _Pragma("unroll")                                                \
            for (int lb = 0; lb < 16; lb++) {                                \
                float4 kb = sK4[lane][lb ^ kswz];                            \
                float4 qa = *(const float4*)&sQ[uu[j0 + 0]][lb * 4];         \
                float4 qb = *(const float4*)&sQ[uu[j0 + 1]][lb * 4];         \
                float4 qc = *(const float4*)&sQ[uu[j0 + 2]][lb * 4];         \
                float4 qd = *(const float4*)&sQ[uu[j0 + 3]][lb * 4];         \
                s0 += kb.x*qa.x + kb.y*qa.y + kb.z*qa.z + kb.w*qa.w;         \
                s1 += kb.x*qb.x + kb.y*qb.y + kb.z*qb.z + kb.w*qb.w;         \
                s2 += kb.x*qc.x + kb.y*qc.y + kb.z*qc.z + kb.w*qc.w;         \
                s3 += kb.x*qd.x + kb.y*qd.y + kb.z*qd.z + kb.w*qd.w;         \
            }                                                                \
            float a0, a1, a2, a3;                                            \
            SLOT(j0 + 0, s0, a0) SLOT(j0 + 1, s1, a1)                        \
            SLOT(j0 + 2, s2, a2) SLOT(j0 + 3, s3, a3)                        \
            float p0 = 0.f, p1 = 0.f, p2 = 0.f, p3 = 0.f;                    \
            _Pragma("unroll")                                                \
            for (int kk = 0; kk < 16; kk++) {                                \
                float4 vb = sV4[lane][kk ^ kswz];                            \
                float4 wa = *(const float4*)&sP[uu[j0 + 0]][kk * 4];         \
                float4 wb = *(const float4*)&sP[uu[j0 + 1]][kk * 4];         \
                float4 wc = *(const float4*)&sP[uu[j0 + 2]][kk * 4];         \
                float4 wd = *(const float4*)&sP[uu[j0 + 3]][kk * 4];         \
                p0 += wa.x*vb.x + wa.y*vb.y + wa.z*vb.z + wa.w*vb.w;         \
                p1 += wb.x*vb.x + wb.y*vb.y + wb.z*vb.z + wb.w*vb.w;         \
                p2 += wc.x*vb.x + wc.y*vb.y + wc.z*vb.z + wc.w*vb.w;         \
                p3 += wd.x*vb.x + wd.y*vb.y + wd.z*vb.z + wd.w*vb.w;         \
            }                                                                \
            o_r[j0 + 0] = o_r[j0 + 0] * a0 + p0;                             \
            o_r[j0 + 1] = o_r[j0 + 1] * a1 + p1;                             \
            o_r[j0 + 2] = o_r[j0 + 2] * a2 + p2;                             \
            o_r[j0 + 3] = o_r[j0 + 3] * a3 + p3;                             \
        }
#define SLOT(jj, sv, av) {                                                   \
            float sA = (k0 + lane > qq[jj]) ? -INFINITY : sv;                \
            float tm = wmax64(sA);                                           \
            float mnew = fmaxf(m_r[jj], tm);                                 \
            float p = __expf(sA - mnew);                                     \
            float ps = wsum64(p);                                            \
            av = __expf(m_r[jj] - mnew);                                     \
            m_r[jj] = mnew;                                                  \
            l_r[jj] = l_r[jj] * av + ps;                                     \
            sP[uu[jj]][lane] = p; }

        GROUP(0, gmax0)
        GROUP(4, gmax1)
#undef SLOT
#undef GROUP
    }

    // write partials (even ntile==0: combine's lv>0 guard filters NaN/zero).
    // duplicate slots write identical values to identical addresses.
    #pragma unroll
    for (int i = 0; i < 8; i++) {
        size_t s0_ = ((size_t)bh * NCH + c) * U + uu[i];
        Opart[s0_ * 64 + lane] = f2bf(o_r[i]);
        if (lane == 0) { Mp[s0_] = m_r[i]; Lp[s0_] = l_r[i]; }
    }
}

// ---------------------------------------------------------------- kernel 5
__global__ __launch_bounds__(64) void k_combine(
    const unsigned short* __restrict__ Opart, const float* __restrict__ Mp,
    const float* __restrict__ Lp, const int* __restrict__ top,
    float* __restrict__ out, int U)
{
    int b = blockIdx.z, h = blockIdx.y, u = blockIdx.x;
    int bh = b * Hc + h;
    int lane = threadIdx.x;
    int q = top[(size_t)bh * U + u];

    float mv[NCH], lv[NCH];
    float mg = -INFINITY;
    #pragma unroll
    for (int c = 0; c < NCH; c++) {
        size_t s0 = ((size_t)bh * NCH + c) * U + u;
        mv[c] = Mp[s0]; lv[c] = Lp[s0];
        mg = fmaxf(mg, mv[c]);
    }
    float Ls = 0.f, o = 0.f;
    #pragma unroll
    for (int c = 0; c < NCH; c++) {
        if (lv[c] > 0.f) {
            float w = __expf(mv[c] - mg);
            Ls += w * lv[c];
            o  += w * bf2f(Opart[(((size_t)bh * NCH + c) * U + u) * 64 + lane]);
        }
    }
    out[(((size_t)b * Lc + q) * Hc + h) * Dc + lane] = o / Ls;
}

extern "C" void kernel_launch(void* const* d_in, const int* in_sizes, int n_in,
                              void* d_out, int out_size, void* d_ws, size_t ws_size,
                              hipStream_t stream)
{
    const float* Q = (const float*)d_in[0];
    const float* K = (const float*)d_in[1];
    const float* V = (const float*)d_in[2];
    const int* idx = (const int*)d_in[3];
    float* out = (float*)d_out;

    int S = in_sizes[3] / Lc;   // sample_k == u == 45

    // ws layout (bytes). M [0,1MB) dead after topk; Opart (bf16, 5.90MB)
    // reuses that region. Mp@6291456 (184KB), Lp@6553600 (184KB),
    // bsum@6815744 (256KB), top@8388608 (11.5KB).
    char* ws = (char*)d_ws;
    float* M              = (float*)ws;
    unsigned short* Opart = (unsigned short*)ws;
    float* Mp    = (float*)(ws + 6291456);
    float* Lp    = (float*)(ws + 6553600);
    float* bsum  = (float*)(ws + 6815744);
    int*   top   = (int*)  (ws + 8388608);

    dim3 blk(256);
    if (S == 45)
        k_meas_t<45><<<dim3(Lc / 4, Hc, Bc), blk, 0, stream>>>(Q, K, idx, M);
    else
        k_meas_dyn  <<<dim3(Lc / 4, Hc, Bc), blk, 0, stream>>>(Q, K, idx, M, S);
    k_topk   <<<dim3(Bc * Hc),        blk, 0, stream>>>(M, top, S);
    k_vsum   <<<dim3(VCH, Hc, Bc),    blk, 0, stream>>>(V, bsum);
    k_scan   <<<dim3(VCH, Hc, Bc),    blk, 0, stream>>>(V, bsum, out);
    k_attn2  <<<dim3(NCH, Hc, Bc), dim3(512), 0, stream>>>(Q, K, V, top, Opart, Mp, Lp, S);
    k_combine<<<dim3(S, Hc, Bc), dim3(64), 0, stream>>>(Opart, Mp, Lp, top, out, S);
}

// Round 7
// 795.281 us; speedup vs baseline: 1.2750x; 1.2750x over previous
//
#include <hip/hip_runtime.h>
#include <math.h>

#define Bc 8
#define Lc 4096
#define Hc 8
#define Dc 64
#define NCH 16             // equal-WORK chunks (sqrt-spaced causal boundaries)
#define VCH 16
#define VROWS (Lc / VCH)   // 256 rows per cumsum chunk

// equal-work causal chunk boundaries: b_c ~= L*(1-sqrt(1-c/16)), 64-aligned
__constant__ int c_cb[NCH + 1] =
    {0, 128, 256, 384, 576, 704, 832, 1024, 1216, 1408,
     1600, 1792, 2048, 2304, 2624, 3072, 4096};

// ---------------------------------------------------------------- helpers
template<int CTRL>
__device__ __forceinline__ float dpp_mov(float v) {
    return __int_as_float(__builtin_amdgcn_update_dpp(
        0, __float_as_int(v), CTRL, 0xF, 0xF, true));
}
template<int CTRL>
__device__ __forceinline__ float dpp_radd(float v) {
    return v + dpp_mov<CTRL>(v);
}
__device__ __forceinline__ float row16_sum(float p) {
    p = dpp_radd<0x128>(p); p = dpp_radd<0x124>(p);
    p = dpp_radd<0x122>(p); p = dpp_radd<0x121>(p);
    return p;
}
__device__ __forceinline__ float wmax64(float v) {
    v = fmaxf(v, dpp_mov<0x128>(v));
    v = fmaxf(v, dpp_mov<0x124>(v));
    v = fmaxf(v, dpp_mov<0x122>(v));
    v = fmaxf(v, dpp_mov<0x121>(v));
    v = fmaxf(v, __shfl_xor(v, 16, 64));
    return fmaxf(v, __shfl_xor(v, 32, 64));
}
__device__ __forceinline__ float wsum64(float v) {
    v = row16_sum(v);
    v += __shfl_xor(v, 16, 64);
    return v + __shfl_xor(v, 32, 64);
}
__device__ __forceinline__ unsigned short f2bf(float f) {  // RNE fp32->bf16
    unsigned int u = __float_as_uint(f);
    u += 0x7FFFu + ((u >> 16) & 1u);
    return (unsigned short)(u >> 16);
}
__device__ __forceinline__ float bf2f(unsigned short s) {
    return __uint_as_float(((unsigned int)s) << 16);
}

// ---------------------------------------------------------------- kernel 1
template<int S>
__global__ __launch_bounds__(256) void k_meas_t(
    const float* __restrict__ Q, const float* __restrict__ K,
    const int* __restrict__ idx, float* __restrict__ M)
{
    constexpr int NIT = (S + 3) / 4;
    int b = blockIdx.z, h = blockIdx.y;
    int w = threadIdx.x >> 6, lane = threadIdx.x & 63;
    int q = blockIdx.x * 4 + w;
    int grp = lane >> 4, gl = lane & 15;

    const float4 qv = *(const float4*)(Q + (((size_t)b * Lc + q) * Hc + h) * Dc + gl * 4);
    const int* ip = idx + (size_t)q * S + grp;
    const float* Kb = K + ((size_t)b * Lc * Hc + h) * Dc + gl * 4;

    int rows[NIT];
    #pragma unroll
    for (int it = 0; it < NIT - 1; it++) rows[it] = ip[it * 4];
    {
        int s = 4 * (NIT - 1) + grp;
        rows[NIT - 1] = ip[(s < S) ? 4 * (NIT - 1) : (S - 1 - grp)];
    }

    float mloc = -INFINITY, sloc = 0.f;
    #pragma unroll
    for (int it = 0; it < NIT; it++) {
        const float4 kw = *(const float4*)(Kb + ((size_t)rows[it] << 9));
        float p = kw.x * qv.x + kw.y * qv.y + kw.z * qv.z + kw.w * qv.w;
        p = row16_sum(p);
        int s = it * 4 + grp;
        if (s < S) { mloc = fmaxf(mloc, p); sloc += p; }
    }
    mloc = fmaxf(mloc, __shfl_xor(mloc, 16, 64));
    mloc = fmaxf(mloc, __shfl_xor(mloc, 32, 64));
    sloc += __shfl_xor(sloc, 16, 64);
    sloc += __shfl_xor(sloc, 32, 64);

    if (lane == 0)
        M[((size_t)(b * Hc + h)) * Lc + q] = mloc - sloc * (1.0f / (float)Lc);
}

__global__ __launch_bounds__(256) void k_meas_dyn(
    const float* __restrict__ Q, const float* __restrict__ K,
    const int* __restrict__ idx, float* __restrict__ M, int S)
{
    int b = blockIdx.z, h = blockIdx.y;
    int w = threadIdx.x >> 6, lane = threadIdx.x & 63;
    int q = blockIdx.x * 4 + w;
    int grp = lane >> 4, gl = lane & 15;

    const float4 qv = *(const float4*)(Q + (((size_t)b * Lc + q) * Hc + h) * Dc + gl * 4);
    const int* ip = idx + (size_t)q * S;
    const float* Kb = K + ((size_t)b * Lc * Hc + h) * Dc + gl * 4;

    float mloc = -INFINITY, sloc = 0.f;
    int niter = (S + 3) >> 2;
    for (int it = 0; it < niter; it++) {
        int s = it * 4 + grp;
        int ii = s < S ? s : S - 1;
        int row = ip[ii];
        const float4 kw = *(const float4*)(Kb + ((size_t)row << 9));
        float p = kw.x * qv.x + kw.y * qv.y + kw.z * qv.z + kw.w * qv.w;
        p = row16_sum(p);
        if (s < S) { mloc = fmaxf(mloc, p); sloc += p; }
    }
    mloc = fmaxf(mloc, __shfl_xor(mloc, 16, 64));
    mloc = fmaxf(mloc, __shfl_xor(mloc, 32, 64));
    sloc += __shfl_xor(sloc, 16, 64);
    sloc += __shfl_xor(sloc, 32, 64);
    if (lane == 0)
        M[((size_t)(b * Hc + h)) * Lc + q] = mloc - sloc * (1.0f / (float)Lc);
}

// ---------------------------------------------------------------- kernel 2
// top-U selection, then sort indices ASCENDING (order irrelevant to the
// reference's scatter; gives attn2 sorted query lists for tight cutoffs).
__global__ __launch_bounds__(256) void k_topk(
    const float* __restrict__ M, int* __restrict__ top, int U)
{
    int bh = blockIdx.x;
    int tid = threadIdx.x;
    const float* m = M + (size_t)bh * Lc;

    unsigned long long key[16];
    #pragma unroll
    for (int j = 0; j < 16; j++) {
        int i = tid * 16 + j;
        unsigned int u = __float_as_uint(m[i]);
        u ^= (unsigned int)(((int)u >> 31)) | 0x80000000u;
        key[j] = ((unsigned long long)u << 32) | (unsigned int)i;
    }
    unsigned long long myb = key[0];
    #pragma unroll
    for (int j = 1; j < 16; j++) myb = key[j] > myb ? key[j] : myb;

    __shared__ unsigned long long swave[2][4];
    __shared__ int swin[256];

    for (int u = 0; u < U; u++) {
        unsigned long long wmax = myb;
        #pragma unroll
        for (int o = 32; o >= 1; o >>= 1) {
            unsigned long long t = __shfl_xor(wmax, o, 64);
            wmax = t > wmax ? t : wmax;
        }
        if ((tid & 63) == 0) swave[u & 1][tid >> 6] = wmax;
        __syncthreads();
        unsigned long long w0 = swave[u & 1][0], w1 = swave[u & 1][1];
        unsigned long long w2 = swave[u & 1][2], w3 = swave[u & 1][3];
        unsigned long long a = w0 > w1 ? w0 : w1;
        unsigned long long c = w2 > w3 ? w2 : w3;
        unsigned long long win = a > c ? a : c;
        int widx = (int)(win & 0xFFFFFFFFu);
        if (tid == 0) swin[u] = widx;
        if (tid == (widx >> 4)) {
            #pragma unroll
            for (int j = 0; j < 16; j++) if (j == (widx & 15)) key[j] = 0ull;
            unsigned long long b2 = key[0];
            #pragma unroll
            for (int j = 1; j < 16; j++) b2 = key[j] > b2 ? key[j] : b2;
            myb = b2;
        }
    }
    __syncthreads();
    for (int ph = 0; ph < U; ph++) {
        int i = 2 * tid + (ph & 1);
        if (i + 1 < U) {
            int a = swin[i], b2 = swin[i + 1];
            if (a > b2) { swin[i] = b2; swin[i + 1] = a; }
        }
        __syncthreads();
    }
    if (tid < U) top[(size_t)bh * U + tid] = swin[tid];
}

// ---------------------------------------------------------------- kernel 3a
__global__ __launch_bounds__(256) void k_vsum(
    const float* __restrict__ V, float* __restrict__ bsum)
{
    int b = blockIdx.z, h = blockIdx.y, c = blockIdx.x;
    int d = threadIdx.x & 63, g = threadIdx.x >> 6;
    __shared__ float part[4][64];
    float s = 0.f;
    int r0 = c * VROWS;
    for (int r = r0 + g; r < r0 + VROWS; r += 4)
        s += V[(((size_t)b * Lc + r) * Hc + h) * Dc + d];
    part[g][d] = s;
    __syncthreads();
    if (g == 0)
        bsum[(((size_t)(b * Hc + h)) * VCH + c) * 64 + d] =
            part[0][d] + part[1][d] + part[2][d] + part[3][d];
}

// ---------------------------------------------------------------- kernel 3b
// scan within each 256-row chunk; V rows cached in registers (kills 2nd read)
__global__ __launch_bounds__(256) void k_scan(
    const float* __restrict__ V, const float* __restrict__ bsum,
    float* __restrict__ out)
{
    int b = blockIdx.z, h = blockIdx.y, c = blockIdx.x;
    int d = threadIdx.x & 63, g = threadIdx.x >> 6;
    int bh = b * Hc + h;
    __shared__ float gtot[4][64];
    __shared__ float goff[4][64];

    float base = 0.f;
    for (int cc = 0; cc < c; cc++)
        base += bsum[((size_t)bh * VCH + cc) * 64 + d];

    int gs = c * VROWS + g * 64;
    const float* vb = V + (((size_t)b * Lc + gs) * Hc + h) * Dc + d;

    float vloc[64];
    float gsum = 0.f;
    #pragma unroll
    for (int i = 0; i < 64; i++) {
        vloc[i] = vb[(size_t)i * (Hc * Dc)];
        gsum += vloc[i];
    }
    gtot[g][d] = gsum;
    __syncthreads();
    if (g == 0) {
        float run = base;
        for (int gg = 0; gg < 4; gg++) { goff[gg][d] = run; run += gtot[gg][d]; }
    }
    __syncthreads();
    float run = goff[g][d];
    float* ob = out + (((size_t)b * Lc + gs) * Hc + h) * Dc + d;
    #pragma unroll
    for (int i = 0; i < 64; i++) {
        run += vloc[i];
        ob[(size_t)i * (Hc * Dc)] = run;
    }
}

// ---------------------------------------------------------------- kernel 4
// flash attention over selected (globally sorted) queries.
// 512-thread blocks (8 waves share one staged tile), 8 slots/wave.
// __launch_bounds__(512, 2): 2 blocks/CU = 16 waves/CU, VGPR cap 128
// (R6's (512,4) forced VGPR=64 -> 310MB scratch spills; that was the bug).
__global__ __launch_bounds__(512, 2) void k_attn2(
    const float* __restrict__ Q, const float* __restrict__ K,
    const float* __restrict__ V, const int* __restrict__ top,
    unsigned short* __restrict__ Opart, float* __restrict__ Mp,
    float* __restrict__ Lp, int U)
{
    int b = blockIdx.z, h = blockIdx.y, c = blockIdx.x;
    int bh = b * Hc + h;
    int tid = threadIdx.x;
    int lane = tid & 63, g = tid >> 6;          // g = wave id 0..7

    __shared__ float4 sK4[64][16];   // 16KB  row=key, col=lb^(key&7)
    __shared__ float4 sV4[64][16];   // 16KB  row=d, col=(key>>2)^(d&7)
    __shared__ float  sQ[48][64];    // 12KB
    __shared__ float  sP[48][64];    // 12KB  (row u touched only by wave u%8)
    __shared__ int    sqi[48];

    if (tid < U) sqi[tid] = top[(size_t)bh * U + tid];
    __syncthreads();
    for (int u = g; u < U; u += 8)
        sQ[u][lane] = Q[(((size_t)b * Lc + sqi[u]) * Hc + h) * Dc + lane] * 0.125f;

    int qbm = sqi[U - 1];            // globally sorted -> max q
    // 8 strided slots per wave; invalid -> dup of slot 0 (dup work is tiny;
    // dup writes same value to same address)
    int uu[8], qq[8];
    #pragma unroll
    for (int i = 0; i < 8; i++) {
        int u = g + 8 * i;
        uu[i] = (u < U) ? u : g;
        qq[i] = sqi[uu[i]];
    }
    int gmax0 = max(max(qq[0], qq[1]), max(qq[2], qq[3]));
    int gmax1 = max(max(qq[4], qq[5]), max(qq[6], qq[7]));

    float m_r[8], l_r[8], o_r[8];
    #pragma unroll
    for (int i = 0; i < 8; i++) { m_r[i] = -INFINITY; l_r[i] = 0.f; o_r[i] = 0.f; }

    int k0c = c_cb[c], k1c = c_cb[c + 1];
    int ntile = 0;
    if (qbm >= k0c) ntile = (min(qbm, k1c - 1) - k0c) / 64 + 1;
    int kswz = lane & 7;

    for (int t = 0; t < ntile; t++) {
        int k0 = k0c + t * 64;
        __syncthreads();   // previous tile consumed; sQ/sqi writes ordered
        {   // stage: wave g covers dims g*8 .. g*8+7 (2 float4 per thread)
            const float* kp = K + (((size_t)b * Lc + k0 + lane) * Hc + h) * Dc + g * 8;
            const float* vp = V + (((size_t)b * Lc + k0 + lane) * Hc + h) * Dc + g * 8;
            #pragma unroll
            for (int i = 0; i < 2; i++) {
                float4 kw = *(const float4*)(kp + i * 4);
                float4 vw = *(const float4*)(vp + i * 4);
                int lb = g * 2 + i;
                sK4[lane][lb ^ kswz] = kw;
                int d0 = lb * 4;
                ((float*)&sV4[d0 + 0][(lane >> 2) ^ ((d0 + 0) & 7)])[lane & 3] = vw.x;
                ((float*)&sV4[d0 + 1][(lane >> 2) ^ ((d0 + 1) & 7)])[lane & 3] = vw.y;
                ((float*)&sV4[d0 + 2][(lane >> 2) ^ ((d0 + 2) & 7)])[lane & 3] = vw.z;
                ((float*)&sV4[d0 + 3][(lane >> 2) ^ ((d0 + 3) & 7)])[lane & 3] = vw.w;
            }
        }
        __syncthreads();

#define GROUP(j0, gmax)                                                      \
        if (k0 <= gmax) {                                                    \
            float s0 = 0.f, s1 = 0.f, s2 = 0.f, s3 = 0.f;                    \
            _Pragma("unroll")                                                \
            for (int lb = 0; lb < 16; lb++) {                                \
                float4 kb = sK4[lane][lb ^ kswz];                            \
                float4 qa = *(const float4*)&sQ[uu[j0 + 0]][lb * 4];         \
                float4 qb = *(const float4*)&sQ[uu[j0 + 1]][lb * 4];         \
                float4 qc = *(const float4*)&sQ[uu[j0 + 2]][lb * 4];         \
                float4 qd = *(const float4*)&sQ[uu[j0 + 3]][lb * 4];         \
                s0 += kb.x*qa.x + kb.y*qa.y + kb.z*qa.z + kb.w*qa.w;         \
                s1 += kb.x*qb.x + kb.y*qb.y + kb.z*qb.z + kb.w*qb.w;         \
                s2 += kb.x*qc.x + kb.y*qc.y + kb.z*qc.z + kb.w*qc.w;         \
                s3 += kb.x*qd.x + kb.y*qd.y + kb.z*qd.z + kb.w*qd.w;         \
            }                                                                \
            float a0, a1, a2, a3;                                            \
            SLOT(j0 + 0, s0, a0) SLOT(j0 + 1, s1, a1)                        \
            SLOT(j0 + 2, s2, a2) SLOT(j0 + 3, s3, a3)                        \
            float p0 = 0.f, p1 = 0.f, p2 = 0.f, p3 = 0.f;                    \
            _Pragma("unroll")                                                \
            for (int kk = 0; kk < 16; kk++) {                                \
                float4 vb = sV4[lane][kk ^ kswz];                            \
                float4 wa = *(const float4*)&sP[uu[j0 + 0]][kk * 4];         \
                float4 wb = *(const float4*)&sP[uu[j0 + 1]][kk * 4];         \
                float4 wc = *(const float4*)&sP[uu[j0 + 2]][kk * 4];         \
                float4 wd = *(const float4*)&sP[uu[j0 + 3]][kk * 4];         \
                p0 += wa.x*vb.x + wa.y*vb.y + wa.z*vb.z + wa.w*vb.w;         \
                p1 += wb.x*vb.x + wb.y*vb.y + wb.z*vb.z + wb.w*vb.w;         \
                p2 += wc.x*vb.x + wc.y*vb.y + wc.z*vb.z + wc.w*vb.w;         \
                p3 += wd.x*vb.x + wd.y*vb.y + wd.z*vb.z + wd.w*vb.w;         \
            }                                                                \
            o_r[j0 + 0] = o_r[j0 + 0] * a0 + p0;                             \
            o_r[j0 + 1] = o_r[j0 + 1] * a1 + p1;                             \
            o_r[j0 + 2] = o_r[j0 + 2] * a2 + p2;                             \
            o_r[j0 + 3] = o_r[j0 + 3] * a3 + p3;                             \
        }
#define SLOT(jj, sv, av) {                                                   \
            float sA = (k0 + lane > qq[jj]) ? -INFINITY : sv;                \
            float tm = wmax64(sA);                                           \
            float mnew = fmaxf(m_r[jj], tm);                                 \
            float p = __expf(sA - mnew);                                     \
            float ps = wsum64(p);                                            \
            av = __expf(m_r[jj] - mnew);                                     \
            m_r[jj] = mnew;                                                  \
            l_r[jj] = l_r[jj] * av + ps;                                     \
            sP[uu[jj]][lane] = p; }

        GROUP(0, gmax0)
        GROUP(4, gmax1)
#undef SLOT
#undef GROUP
    }

    // write partials (even ntile==0: combine's lv>0 guard filters NaN/zero).
    // duplicate slots write identical values to identical addresses.
    #pragma unroll
    for (int i = 0; i < 8; i++) {
        size_t s0_ = ((size_t)bh * NCH + c) * U + uu[i];
        Opart[s0_ * 64 + lane] = f2bf(o_r[i]);
        if (lane == 0) { Mp[s0_] = m_r[i]; Lp[s0_] = l_r[i]; }
    }
}

// ---------------------------------------------------------------- kernel 5
__global__ __launch_bounds__(64) void k_combine(
    const unsigned short* __restrict__ Opart, const float* __restrict__ Mp,
    const float* __restrict__ Lp, const int* __restrict__ top,
    float* __restrict__ out, int U)
{
    int b = blockIdx.z, h = blockIdx.y, u = blockIdx.x;
    int bh = b * Hc + h;
    int lane = threadIdx.x;
    int q = top[(size_t)bh * U + u];

    float mv[NCH], lv[NCH];
    float mg = -INFINITY;
    #pragma unroll
    for (int c = 0; c < NCH; c++) {
        size_t s0 = ((size_t)bh * NCH + c) * U + u;
        mv[c] = Mp[s0]; lv[c] = Lp[s0];
        mg = fmaxf(mg, mv[c]);
    }
    float Ls = 0.f, o = 0.f;
    #pragma unroll
    for (int c = 0; c < NCH; c++) {
        if (lv[c] > 0.f) {
            float w = __expf(mv[c] - mg);
            Ls += w * lv[c];
            o  += w * bf2f(Opart[(((size_t)bh * NCH + c) * U + u) * 64 + lane]);
        }
    }
    out[(((size_t)b * Lc + q) * Hc + h) * Dc + lane] = o / Ls;
}

extern "C" void kernel_launch(void* const* d_in, const int* in_sizes, int n_in,
                              void* d_out, int out_size, void* d_ws, size_t ws_size,
                              hipStream_t stream)
{
    const float* Q = (const float*)d_in[0];
    const float* K = (const float*)d_in[1];
    const float* V = (const float*)d_in[2];
    const int* idx = (const int*)d_in[3];
    float* out = (float*)d_out;

    int S = in_sizes[3] / Lc;   // sample_k == u == 45

    // ws layout (bytes). M [0,1MB) dead after topk; Opart (bf16, 5.90MB)
    // reuses that region. Mp@6291456 (184KB), Lp@6553600 (184KB),
    // bsum@6815744 (256KB), top@8388608 (11.5KB).
    char* ws = (char*)d_ws;
    float* M              = (float*)ws;
    unsigned short* Opart = (unsigned short*)ws;
    float* Mp    = (float*)(ws + 6291456);
    float* Lp    = (float*)(ws + 6553600);
    float* bsum  = (float*)(ws + 6815744);
    int*   top   = (int*)  (ws + 8388608);

    dim3 blk(256);
    if (S == 45)
        k_meas_t<45><<<dim3(Lc / 4, Hc, Bc), blk, 0, stream>>>(Q, K, idx, M);
    else
        k_meas_dyn  <<<dim3(Lc / 4, Hc, Bc), blk, 0, stream>>>(Q, K, idx, M, S);
    k_topk   <<<dim3(Bc * Hc),        blk, 0, stream>>>(M, top, S);
    k_vsum   <<<dim3(VCH, Hc, Bc),    blk, 0, stream>>>(V, bsum);
    k_scan   <<<dim3(VCH, Hc, Bc),    blk, 0, stream>>>(V, bsum, out);
    k_attn2  <<<dim3(NCH, Hc, Bc), dim3(512), 0, stream>>>(Q, K, V, top, Opart, Mp, Lp, S);
    k_combine<<<dim3(S, Hc, Bc), dim3(64), 0, stream>>>(Opart, Mp, Lp, top, out, S);
}

// Round 8
// 531.114 us; speedup vs baseline: 1.9091x; 1.4974x over previous
//
#include <hip/hip_runtime.h>
#include <math.h>

#define Bc 8
#define Lc 4096
#define Hc 8
#define Dc 64
#define NCH 16             // equal-work chunks, boundaries multiple of 128
#define VCH 16
#define VROWS (Lc / VCH)   // 256 rows per cumsum chunk

// equal-work causal chunk boundaries (128-aligned for the MFMA tile)
__constant__ int c_cb[NCH + 1] =
    {0, 128, 256, 384, 512, 768, 896, 1024, 1152, 1408,
     1536, 1792, 2048, 2304, 2688, 3072, 4096};

typedef __attribute__((ext_vector_type(8))) short bfrag;   // 8 bf16 = 4 VGPR
typedef __attribute__((ext_vector_type(4))) float f32x4;

// ---------------------------------------------------------------- helpers
template<int CTRL>
__device__ __forceinline__ float dpp_mov(float v) {
    return __int_as_float(__builtin_amdgcn_update_dpp(
        0, __float_as_int(v), CTRL, 0xF, 0xF, true));
}
template<int CTRL>
__device__ __forceinline__ float dpp_radd(float v) {
    return v + dpp_mov<CTRL>(v);
}
__device__ __forceinline__ float row16_sum(float p) {
    p = dpp_radd<0x128>(p); p = dpp_radd<0x124>(p);
    p = dpp_radd<0x122>(p); p = dpp_radd<0x121>(p);
    return p;
}
__device__ __forceinline__ float row16_max(float v) {
    v = fmaxf(v, dpp_mov<0x128>(v));
    v = fmaxf(v, dpp_mov<0x124>(v));
    v = fmaxf(v, dpp_mov<0x122>(v));
    v = fmaxf(v, dpp_mov<0x121>(v));
    return v;
}
__device__ __forceinline__ unsigned short f2bf(float f) {  // RNE fp32->bf16
    unsigned int u = __float_as_uint(f);
    u += 0x7FFFu + ((u >> 16) & 1u);
    return (unsigned short)(u >> 16);
}
__device__ __forceinline__ float bf2f(unsigned short s) {
    return __uint_as_float(((unsigned int)s) << 16);
}

// ---------------------------------------------------------------- kernel 1
template<int S>
__global__ __launch_bounds__(256) void k_meas_t(
    const float* __restrict__ Q, const float* __restrict__ K,
    const int* __restrict__ idx, float* __restrict__ M)
{
    constexpr int NIT = (S + 3) / 4;
    int b = blockIdx.z, h = blockIdx.y;
    int w = threadIdx.x >> 6, lane = threadIdx.x & 63;
    int q = blockIdx.x * 4 + w;
    int grp = lane >> 4, gl = lane & 15;

    const float4 qv = *(const float4*)(Q + (((size_t)b * Lc + q) * Hc + h) * Dc + gl * 4);
    const int* ip = idx + (size_t)q * S + grp;
    const float* Kb = K + ((size_t)b * Lc * Hc + h) * Dc + gl * 4;

    int rows[NIT];
    #pragma unroll
    for (int it = 0; it < NIT - 1; it++) rows[it] = ip[it * 4];
    {
        int s = 4 * (NIT - 1) + grp;
        rows[NIT - 1] = ip[(s < S) ? 4 * (NIT - 1) : (S - 1 - grp)];
    }

    float mloc = -INFINITY, sloc = 0.f;
    #pragma unroll
    for (int it = 0; it < NIT; it++) {
        const float4 kw = *(const float4*)(Kb + ((size_t)rows[it] << 9));
        float p = kw.x * qv.x + kw.y * qv.y + kw.z * qv.z + kw.w * qv.w;
        p = row16_sum(p);
        int s = it * 4 + grp;
        if (s < S) { mloc = fmaxf(mloc, p); sloc += p; }
    }
    mloc = fmaxf(mloc, __shfl_xor(mloc, 16, 64));
    mloc = fmaxf(mloc, __shfl_xor(mloc, 32, 64));
    sloc += __shfl_xor(sloc, 16, 64);
    sloc += __shfl_xor(sloc, 32, 64);

    if (lane == 0)
        M[((size_t)(b * Hc + h)) * Lc + q] = mloc - sloc * (1.0f / (float)Lc);
}

__global__ __launch_bounds__(256) void k_meas_dyn(
    const float* __restrict__ Q, const float* __restrict__ K,
    const int* __restrict__ idx, float* __restrict__ M, int S)
{
    int b = blockIdx.z, h = blockIdx.y;
    int w = threadIdx.x >> 6, lane = threadIdx.x & 63;
    int q = blockIdx.x * 4 + w;
    int grp = lane >> 4, gl = lane & 15;

    const float4 qv = *(const float4*)(Q + (((size_t)b * Lc + q) * Hc + h) * Dc + gl * 4);
    const int* ip = idx + (size_t)q * S;
    const float* Kb = K + ((size_t)b * Lc * Hc + h) * Dc + gl * 4;

    float mloc = -INFINITY, sloc = 0.f;
    int niter = (S + 3) >> 2;
    for (int it = 0; it < niter; it++) {
        int s = it * 4 + grp;
        int ii = s < S ? s : S - 1;
        int row = ip[ii];
        const float4 kw = *(const float4*)(Kb + ((size_t)row << 9));
        float p = kw.x * qv.x + kw.y * qv.y + kw.z * qv.z + kw.w * qv.w;
        p = row16_sum(p);
        if (s < S) { mloc = fmaxf(mloc, p); sloc += p; }
    }
    mloc = fmaxf(mloc, __shfl_xor(mloc, 16, 64));
    mloc = fmaxf(mloc, __shfl_xor(mloc, 32, 64));
    sloc += __shfl_xor(sloc, 16, 64);
    sloc += __shfl_xor(sloc, 32, 64);
    if (lane == 0)
        M[((size_t)(b * Hc + h)) * Lc + q] = mloc - sloc * (1.0f / (float)Lc);
}

// ---------------------------------------------------------------- kernel 2
// top-U selection, then sort indices ASCENDING (order irrelevant to the
// reference's scatter).
__global__ __launch_bounds__(256) void k_topk(
    const float* __restrict__ M, int* __restrict__ top, int U)
{
    int bh = blockIdx.x;
    int tid = threadIdx.x;
    const float* m = M + (size_t)bh * Lc;

    unsigned long long key[16];
    #pragma unroll
    for (int j = 0; j < 16; j++) {
        int i = tid * 16 + j;
        unsigned int u = __float_as_uint(m[i]);
        u ^= (unsigned int)(((int)u >> 31)) | 0x80000000u;
        key[j] = ((unsigned long long)u << 32) | (unsigned int)i;
    }
    unsigned long long myb = key[0];
    #pragma unroll
    for (int j = 1; j < 16; j++) myb = key[j] > myb ? key[j] : myb;

    __shared__ unsigned long long swave[2][4];
    __shared__ int swin[256];

    for (int u = 0; u < U; u++) {
        unsigned long long wmax = myb;
        #pragma unroll
        for (int o = 32; o >= 1; o >>= 1) {
            unsigned long long t = __shfl_xor(wmax, o, 64);
            wmax = t > wmax ? t : wmax;
        }
        if ((tid & 63) == 0) swave[u & 1][tid >> 6] = wmax;
        __syncthreads();
        unsigned long long w0 = swave[u & 1][0], w1 = swave[u & 1][1];
        unsigned long long w2 = swave[u & 1][2], w3 = swave[u & 1][3];
        unsigned long long a = w0 > w1 ? w0 : w1;
        unsigned long long c = w2 > w3 ? w2 : w3;
        unsigned long long win = a > c ? a : c;
        int widx = (int)(win & 0xFFFFFFFFu);
        if (tid == 0) swin[u] = widx;
        if (tid == (widx >> 4)) {
            #pragma unroll
            for (int j = 0; j < 16; j++) if (j == (widx & 15)) key[j] = 0ull;
            unsigned long long b2 = key[0];
            #pragma unroll
            for (int j = 1; j < 16; j++) b2 = key[j] > b2 ? key[j] : b2;
            myb = b2;
        }
    }
    __syncthreads();
    for (int ph = 0; ph < U; ph++) {
        int i = 2 * tid + (ph & 1);
        if (i + 1 < U) {
            int a = swin[i], b2 = swin[i + 1];
            if (a > b2) { swin[i] = b2; swin[i + 1] = a; }
        }
        __syncthreads();
    }
    if (tid < U) top[(size_t)bh * U + tid] = swin[tid];
}

// ---------------------------------------------------------------- kernel 3a
__global__ __launch_bounds__(256) void k_vsum(
    const float* __restrict__ V, float* __restrict__ bsum)
{
    int b = blockIdx.z, h = blockIdx.y, c = blockIdx.x;
    int d = threadIdx.x & 63, g = threadIdx.x >> 6;
    __shared__ float part[4][64];
    float s = 0.f;
    int r0 = c * VROWS;
    for (int r = r0 + g; r < r0 + VROWS; r += 4)
        s += V[(((size_t)b * Lc + r) * Hc + h) * Dc + d];
    part[g][d] = s;
    __syncthreads();
    if (g == 0)
        bsum[(((size_t)(b * Hc + h)) * VCH + c) * 64 + d] =
            part[0][d] + part[1][d] + part[2][d] + part[3][d];
}

// ---------------------------------------------------------------- kernel 3b
__global__ __launch_bounds__(256) void k_scan(
    const float* __restrict__ V, const float* __restrict__ bsum,
    float* __restrict__ out)
{
    int b = blockIdx.z, h = blockIdx.y, c = blockIdx.x;
    int d = threadIdx.x & 63, g = threadIdx.x >> 6;
    int bh = b * Hc + h;
    __shared__ float gtot[4][64];
    __shared__ float goff[4][64];

    float base = 0.f;
    for (int cc = 0; cc < c; cc++)
        base += bsum[((size_t)bh * VCH + cc) * 64 + d];

    int gs = c * VROWS + g * 64;
    const float* vb = V + (((size_t)b * Lc + gs) * Hc + h) * Dc + d;

    float vloc[64];
    float gsum = 0.f;
    #pragma unroll
    for (int i = 0; i < 64; i++) {
        vloc[i] = vb[(size_t)i * (Hc * Dc)];
        gsum += vloc[i];
    }
    gtot[g][d] = gsum;
    __syncthreads();
    if (g == 0) {
        float run = base;
        for (int gg = 0; gg < 4; gg++) { goff[gg][d] = run; run += gtot[gg][d]; }
    }
    __syncthreads();
    float run = goff[g][d];
    float* ob = out + (((size_t)b * Lc + gs) * Hc + h) * Dc + d;
    #pragma unroll
    for (int i = 0; i < 64; i++) {
        run += vloc[i];
        ob[(size_t)i * (Hc * Dc)] = run;
    }
}

// ---------------------------------------------------------------- kernel 4
// MFMA flash attention. Block = 4 waves, tile = 128 keys; wave w owns keys
// [32w, 32w+32) with its own online softmax; partials merged in-block.
// Q lives in registers as A-fragments. K bf16 [key][d], V bf16 [d][key],
// both XOR-swizzled at 16B units -> conflict-free ds_read_b128 fragments.
__global__ __launch_bounds__(256) void k_attn2(
    const float* __restrict__ Q, const float* __restrict__ K,
    const float* __restrict__ V, const int* __restrict__ top,
    unsigned short* __restrict__ Opart, float* __restrict__ Mp,
    float* __restrict__ Lp, int U)
{
    int b = blockIdx.z, h = blockIdx.y, c = blockIdx.x;
    int bh = b * Hc + h;
    int tid = threadIdx.x;
    int lane = tid & 63, w = tid >> 6;
    int l15 = lane & 15, l4 = lane >> 4;

    __shared__ __align__(16) unsigned short sK[128 * 64];     // 16KB [key][d]
    __shared__ __align__(16) unsigned short sV[64 * 128];     // 16KB [d][key]
    __shared__ __align__(16) unsigned short sP[4 * 48 * 40];  // 15360B per-wave P[q][key]
    __shared__ float sMw[4][48], sLw[4][48];
    __shared__ float sMg[48], sLg[48];
    __shared__ int   sqi[48];
    float* sO = (float*)sP;   // [48][64] f32 (12KB) reuses P after final barrier

    if (tid < 48) sqi[tid] = top[(size_t)bh * U + min(tid, U - 1)];
    __syncthreads();
    int qbm = sqi[47];

    // per-lane query values for this lane's (rb, reg) output slots
    int qv_[3][4];
    #pragma unroll
    for (int rb = 0; rb < 3; rb++)
        #pragma unroll
        for (int r = 0; r < 4; r++)
            qv_[rb][r] = sqi[rb * 16 + l4 * 4 + r];

    // Q A-fragments in registers: qf[rb][ks] = Q[row=l15+16rb][d=32ks+8*l4+j]*0.125
    bfrag qf[3][2];
    #pragma unroll
    for (int rb = 0; rb < 3; rb++) {
        int qrow = sqi[rb * 16 + l15];
        const float* qp = Q + (((size_t)b * Lc + qrow) * Hc + h) * Dc + l4 * 8;
        #pragma unroll
        for (int ks = 0; ks < 2; ks++) {
            float4 x = *(const float4*)(qp + ks * 32);
            float4 y = *(const float4*)(qp + ks * 32 + 4);
            bfrag f;
            f[0] = (short)f2bf(x.x * 0.125f); f[1] = (short)f2bf(x.y * 0.125f);
            f[2] = (short)f2bf(x.z * 0.125f); f[3] = (short)f2bf(x.w * 0.125f);
            f[4] = (short)f2bf(y.x * 0.125f); f[5] = (short)f2bf(y.y * 0.125f);
            f[6] = (short)f2bf(y.z * 0.125f); f[7] = (short)f2bf(y.w * 0.125f);
            qf[rb][ks] = f;
        }
    }

    float m_[3][4], l_[3][4];
    f32x4 oacc[3][4];
    #pragma unroll
    for (int rb = 0; rb < 3; rb++)
        #pragma unroll
        for (int r = 0; r < 4; r++) {
            m_[rb][r] = -1e30f; l_[rb][r] = 0.f;
            oacc[rb][r] = (f32x4){0.f, 0.f, 0.f, 0.f};
        }

    int k0c = c_cb[c], k1c = c_cb[c + 1];
    int ntile = 0;
    if (qbm >= k0c) ntile = (min(qbm, k1c - 1) - k0c) / 128 + 1;

    for (int t = 0; t < ntile; t++) {
        int k0 = k0c + t * 128;
        __syncthreads();   // previous tile fully consumed
        {   // stage: thread -> key kt = tid>>1, d-half dh = (tid&1)*32
            int kt = tid >> 1, dh = (tid & 1) * 32;
            const float* kp = K + (((size_t)b * Lc + k0 + kt) * Hc + h) * Dc + dh;
            const float* vp = V + (((size_t)b * Lc + k0 + kt) * Hc + h) * Dc + dh;
            #pragma unroll
            for (int u = 0; u < 4; u++) {
                float4 x = *(const float4*)(kp + u * 8);
                float4 y = *(const float4*)(kp + u * 8 + 4);
                bfrag f;
                f[0] = (short)f2bf(x.x); f[1] = (short)f2bf(x.y);
                f[2] = (short)f2bf(x.z); f[3] = (short)f2bf(x.w);
                f[4] = (short)f2bf(y.x); f[5] = (short)f2bf(y.y);
                f[6] = (short)f2bf(y.z); f[7] = (short)f2bf(y.w);
                int unit = (dh >> 3) + u;
                *(bfrag*)(&sK[kt * 64 + ((unit ^ (kt & 7)) << 3)]) = f;
            }
            #pragma unroll
            for (int u = 0; u < 8; u++) {
                float4 x = *(const float4*)(vp + u * 4);
                #pragma unroll
                for (int j = 0; j < 4; j++) {
                    int d = dh + u * 4 + j;
                    float val = (j == 0) ? x.x : (j == 1) ? x.y : (j == 2) ? x.z : x.w;
                    sV[d * 128 + (((kt >> 3) ^ (d & 15)) << 3) + (kt & 7)] = f2bf(val);
                }
            }
        }
        __syncthreads();

        if (k0 + w * 32 <= qbm) {
            // ---- QK^T: 12 MFMAs (2 col-blocks x 3 row-blocks x 2 k-steps)
            f32x4 sc[3][2];
            #pragma unroll
            for (int cb = 0; cb < 2; cb++) {
                int key = w * 32 + cb * 16 + l15;
                bfrag kb0 = *(const bfrag*)(&sK[key * 64 + (((0 * 4 + l4) ^ (key & 7)) << 3)]);
                bfrag kb1 = *(const bfrag*)(&sK[key * 64 + (((1 * 4 + l4) ^ (key & 7)) << 3)]);
                #pragma unroll
                for (int rb = 0; rb < 3; rb++) {
                    f32x4 z = {0.f, 0.f, 0.f, 0.f};
                    z = __builtin_amdgcn_mfma_f32_16x16x32_bf16(qf[rb][0], kb0, z, 0, 0, 0);
                    z = __builtin_amdgcn_mfma_f32_16x16x32_bf16(qf[rb][1], kb1, z, 0, 0, 0);
                    sc[rb][cb] = z;
                }
            }
            // ---- online softmax per (rb, reg); write P (bf16) for PV
            int key0 = k0 + w * 32 + l15;
            #pragma unroll
            for (int rb = 0; rb < 3; rb++) {
                #pragma unroll
                for (int r = 0; r < 4; r++) {
                    int qv = qv_[rb][r];
                    float s0 = (key0 > qv)      ? -INFINITY : sc[rb][0][r];
                    float s1 = (key0 + 16 > qv) ? -INFINITY : sc[rb][1][r];
                    float tm = row16_max(fmaxf(s0, s1));
                    float mnew = fmaxf(fmaxf(m_[rb][r], tm), -1e30f);
                    float al = __expf(m_[rb][r] - mnew);
                    float p0 = __expf(s0 - mnew);
                    float p1 = __expf(s1 - mnew);
                    l_[rb][r] = l_[rb][r] * al + row16_sum(p0 + p1);
                    m_[rb][r] = mnew;
                    #pragma unroll
                    for (int cb2 = 0; cb2 < 4; cb2++) oacc[rb][cb2][r] *= al;
                    unsigned short* pw = &sP[(w * 48 + rb * 16 + l4 * 4 + r) * 40];
                    pw[l15]      = f2bf(p0);
                    pw[16 + l15] = f2bf(p1);
                }
            }
            // ---- PV: 12 MFMAs (3 row-blocks x 4 d-col-blocks, K=32 own keys)
            bfrag vbf[4];
            #pragma unroll
            for (int cb2 = 0; cb2 < 4; cb2++) {
                int d = cb2 * 16 + l15;
                int unit = w * 4 + l4;
                vbf[cb2] = *(const bfrag*)(&sV[d * 128 + ((unit ^ (d & 15)) << 3)]);
            }
            #pragma unroll
            for (int rb = 0; rb < 3; rb++) {
                bfrag pa = *(const bfrag*)(&sP[(w * 48 + rb * 16 + l15) * 40 + l4 * 8]);
                #pragma unroll
                for (int cb2 = 0; cb2 < 4; cb2++)
                    oacc[rb][cb2] = __builtin_amdgcn_mfma_f32_16x16x32_bf16(
                        pa, vbf[cb2], oacc[rb][cb2], 0, 0, 0);
            }
        }
    }

    // ---- in-block merge of the 4 wave partials
    __syncthreads();
    if (l15 == 0) {
        #pragma unroll
        for (int rb = 0; rb < 3; rb++)
            #pragma unroll
            for (int r = 0; r < 4; r++) {
                int q = rb * 16 + l4 * 4 + r;
                sMw[w][q] = m_[rb][r];
                sLw[w][q] = l_[rb][r];
            }
    }
    __syncthreads();
    if (tid < 48) {
        float mg = fmaxf(fmaxf(sMw[0][tid], sMw[1][tid]),
                         fmaxf(sMw[2][tid], sMw[3][tid]));
        float lg = 0.f;
        #pragma unroll
        for (int i = 0; i < 4; i++) lg += __expf(sMw[i][tid] - mg) * sLw[i][tid];
        sMg[tid] = mg; sLg[tid] = lg;
    }
    __syncthreads();
    float wt[3][4];
    #pragma unroll
    for (int rb = 0; rb < 3; rb++)
        #pragma unroll
        for (int r = 0; r < 4; r++)
            wt[rb][r] = __expf(m_[rb][r] - sMg[rb * 16 + l4 * 4 + r]);
    // wave-serial accumulate into sO (aliases dead sP)
    for (int i = 0; i < 4; i++) {
        if (w == i) {
            #pragma unroll
            for (int rb = 0; rb < 3; rb++)
                #pragma unroll
                for (int cb2 = 0; cb2 < 4; cb2++)
                    #pragma unroll
                    for (int r = 0; r < 4; r++) {
                        int q = rb * 16 + l4 * 4 + r;
                        int d = cb2 * 16 + l15;
                        float v = oacc[rb][cb2][r] * wt[rb][r];
                        if (i == 0) sO[q * 64 + d] = v;
                        else        sO[q * 64 + d] += v;
                    }
        }
        __syncthreads();
    }
    // write block partial (dup-padded queries u>=U skipped)
    for (int i = 0; i < 12; i++) {
        int u = w + i * 4;
        if (u < U) {
            size_t s0_ = ((size_t)bh * NCH + c) * U + u;
            Opart[s0_ * 64 + lane] = f2bf(sO[u * 64 + lane]);
            if (lane == 0) { Mp[s0_] = sMg[u]; Lp[s0_] = sLg[u]; }
        }
    }
}

// ---------------------------------------------------------------- kernel 5
__global__ __launch_bounds__(64) void k_combine(
    const unsigned short* __restrict__ Opart, const float* __restrict__ Mp,
    const float* __restrict__ Lp, const int* __restrict__ top,
    float* __restrict__ out, int U)
{
    int b = blockIdx.z, h = blockIdx.y, u = blockIdx.x;
    int bh = b * Hc + h;
    int lane = threadIdx.x;
    int q = top[(size_t)bh * U + u];

    float mv[NCH], lv[NCH];
    float mg = -INFINITY;
    #pragma unroll
    for (int c = 0; c < NCH; c++) {
        size_t s0 = ((size_t)bh * NCH + c) * U + u;
        mv[c] = Mp[s0]; lv[c] = Lp[s0];
        mg = fmaxf(mg, mv[c]);
    }
    float Ls = 0.f, o = 0.f;
    #pragma unroll
    for (int c = 0; c < NCH; c++) {
        if (lv[c] > 0.f) {
            float w = __expf(mv[c] - mg);
            Ls += w * lv[c];
            o  += w * bf2f(Opart[(((size_t)bh * NCH + c) * U + u) * 64 + lane]);
        }
    }
    out[(((size_t)b * Lc + q) * Hc + h) * Dc + lane] = o / Ls;
}

extern "C" void kernel_launch(void* const* d_in, const int* in_sizes, int n_in,
                              void* d_out, int out_size, void* d_ws, size_t ws_size,
                              hipStream_t stream)
{
    const float* Q = (const float*)d_in[0];
    const float* K = (const float*)d_in[1];
    const float* V = (const float*)d_in[2];
    const int* idx = (const int*)d_in[3];
    float* out = (float*)d_out;

    int S = in_sizes[3] / Lc;   // sample_k == u == 45

    // ws layout: M [0,1MB) dead after topk; Opart bf16 (5.90MB) reuses it.
    char* ws = (char*)d_ws;
    float* M              = (float*)ws;
    unsigned short* Opart = (unsigned short*)ws;
    float* Mp    = (float*)(ws + 6291456);
    float* Lp    = (float*)(ws + 6553600);
    float* bsum  = (float*)(ws + 6815744);
    int*   top   = (int*)  (ws + 8388608);

    dim3 blk(256);
    if (S == 45)
        k_meas_t<45><<<dim3(Lc / 4, Hc, Bc), blk, 0, stream>>>(Q, K, idx, M);
    else
        k_meas_dyn  <<<dim3(Lc / 4, Hc, Bc), blk, 0, stream>>>(Q, K, idx, M, S);
    k_topk   <<<dim3(Bc * Hc),        blk, 0, stream>>>(M, top, S);
    k_vsum   <<<dim3(VCH, Hc, Bc),    blk, 0, stream>>>(V, bsum);
    k_scan   <<<dim3(VCH, Hc, Bc),    blk, 0, stream>>>(V, bsum, out);
    k_attn2  <<<dim3(NCH, Hc, Bc),    blk, 0, stream>>>(Q, K, V, top, Opart, Mp, Lp, S);
    k_combine<<<dim3(S, Hc, Bc), dim3(64), 0, stream>>>(Opart, Mp, Lp, top, out, S);
}